// Round 6
// baseline (1183.067 us; speedup 1.0000x reference)
//
#include <hip/hip_runtime.h>
#include <stdint.h>
#include <math.h>

#define K_CODES 4096
#define DIM 128
#define N_FLAT 32768      // 32 * 32 * 32
#define HW 1024           // 32*32 spatial per batch

// output offsets (in floats), concat order: quantized_st, loss, perplexity, encodings, indices
#define OFF_Q    0
#define OFF_LOSS 4194304
#define OFF_PERP 4194305
#define OFF_ENC  4194306
#define OFF_IDX  138412034

// workspace offsets (bytes)
#define WS_PACKED 0                       // 32768 * 8 = 262144
#define WS_COUNTS 262144                  // 4096 * 4 = 16384
#define WS_WSQ    278528                  // 4096 * 4 = 16384
#define WS_XSQ    294912                  // 32768 * 4 = 131072
#define WS_PART   425984                  // 1024 * 4 = 4096

// wsd layout: k-group g (8 floats) at col g*8 + (g>>2)*4, row stride 144.
// Read = 2x ds_read_b128 per group; per-instr bank starts {0,4,...,28} mod 32
// each covered 2x -> 2-way aliasing = free (m136). 16B alignment everywhere.
#define WROW 144

// ---------------- K1: w_sq[k] = sum_d w[k][d]^2 ----------------
__global__ __launch_bounds__(64) void wsq_kernel(const float* __restrict__ w,
                                                 float* __restrict__ wsq) {
    int k = blockIdx.x;
    int lane = threadIdx.x;
    float a = w[k * DIM + lane];
    float b = w[k * DIM + lane + 64];
    float s = a * a + b * b;
    #pragma unroll
    for (int o = 32; o > 0; o >>= 1) s += __shfl_down(s, o, 64);
    if (lane == 0) wsq[k] = s;
}

// ---------------- K1b: x_sq[n] = sum_c x[b][c][hw]^2 (strict c order) ------
__global__ __launch_bounds__(256) void xsq_kernel(const float* __restrict__ x,
                                                  float* __restrict__ xsq) {
    int n = blockIdx.x * 256 + threadIdx.x;
    int b = n >> 10, hw = n & 1023;
    const float* xb = x + (size_t)b * (DIM * HW) + hw;
    float s = 0.f;
    #pragma unroll
    for (int c = 0; c < DIM; ++c) {
        float v = xb[c * HW];
        s = fmaf(v, v, s);
    }
    xsq[n] = s;
}

// ---------------- K2: register-tiled distance GEMM + split-K argmin --------
// grid (256 n-tiles, 32 k-tiles), block 256 = 16 kthr x 16 nthr, thread 8n x 8k.
// Block tile 128n x 128k, d chunked by 32 through LDS, register-prefetch of
// the next chunk overlapping FMAs. launch_bounds(256,2): VGPR cap 256 so the
// ~130 live regs (acc 64 + prefetch 32 + frags) fit WITHOUT AGPR-copy/scratch
// games (at (256,4) the allocator pinned 64 arch VGPRs -> 2x VALU + spills).
__global__ __launch_bounds__(256, 2) void dist_argmin(
    const float* __restrict__ x, const float* __restrict__ w,
    const float* __restrict__ wsq, const float* __restrict__ xsq,
    unsigned long long* __restrict__ packed, float* __restrict__ enc)
{
    __shared__ float sm[32 * 128 + 32 * WROW + 256];  // xs | wsd | xsq_s,wsq_s
    float* xs    = sm;                    // [32][128]
    float* wsd   = sm + 4096;             // [32][WROW]
    float* xsq_s = sm + 4096 + 32 * WROW; // [128]
    float* wsq_s = xsq_s + 128;           // [128]

    const int tid  = threadIdx.x;
    const int kthr = tid & 15;
    const int nthr = tid >> 4;
    const int n0   = blockIdx.x * 128;           // same batch b for whole tile
    const int k0   = blockIdx.y * 128;
    const int b    = n0 >> 10;
    const int hw0  = n0 & 1023;

    const float* xg = x + (size_t)b * (DIM * HW) + hw0;  // xg[d*HW + n]
    const float* wg = w + (size_t)k0 * DIM;              // wg[k*DIM + d]

    // per-thread staging coordinates (fixed across chunks)
    const int sdc = tid >> 5;                 // x: d-row within chunk (i*8+sdc)
    const int snc = (tid & 31) << 2;          // x: n column (float4)
    const int sk  = tid >> 3;                 // w: k row (i*32+sk)
    const int sdq = (tid & 7) << 2;           // w: d quad within chunk

    // ---- prefetch chunk 0 into registers (loads issued before any stores) --
    float4 px[4], pw[4];
    #pragma unroll
    for (int i = 0; i < 4; ++i) {
        px[i] = *(const float4*)(xg + (i * 8 + sdc) * HW + snc);
        pw[i] = *(const float4*)(wg + (i * 32 + sk) * DIM + sdq);
    }

    // ---- stage per-row norms ----
    if (tid < 128) {
        xsq_s[tid] = xsq[n0 + tid];
        wsq_s[tid] = wsq[k0 + tid];
    }

    // ---- zero-fill encodings rectangle (writes drain under compute) -------
    {
        float2 z2; z2.x = 0.f; z2.y = 0.f;
        float* ebase = enc + (size_t)n0 * K_CODES + k0;  // 8B-aligned only
        #pragma unroll 4
        for (int i = 0; i < 32; ++i) {
            int idx = i * 256 + tid;
            int r = idx >> 6, c2 = idx & 63;
            *(float2*)(ebase + (size_t)r * K_CODES + c2 * 2) = z2;
        }
    }

    float acc[8][8];
    #pragma unroll
    for (int i = 0; i < 8; ++i)
        #pragma unroll
        for (int j = 0; j < 8; ++j) acc[i][j] = 0.f;

    #pragma unroll
    for (int c0 = 0; c0 < 4; ++c0) {
        const int d0 = c0 * 32;
        if (c0 > 0) __syncthreads();          // prev chunk's LDS reads done
        // write staged registers to LDS
        #pragma unroll
        for (int i = 0; i < 4; ++i) {
            *(float4*)(xs + (i * 8 + sdc) * 128 + snc) = px[i];
            int k = i * 32 + sk;
            int g = k >> 3;
            int col = g * 8 + ((g >> 2) << 2) + (k & 7);
            float4 v = pw[i];
            wsd[(sdq + 0) * WROW + col] = v.x;
            wsd[(sdq + 1) * WROW + col] = v.y;
            wsd[(sdq + 2) * WROW + col] = v.z;
            wsd[(sdq + 3) * WROW + col] = v.w;
        }
        // prefetch next chunk (overlaps with this chunk's FMAs)
        if (c0 < 3) {
            #pragma unroll
            for (int i = 0; i < 4; ++i) {
                px[i] = *(const float4*)(xg + (d0 + 32 + i * 8 + sdc) * HW + snc);
                pw[i] = *(const float4*)(wg + (i * 32 + sk) * DIM + d0 + 32 + sdq);
            }
        }
        __syncthreads();

        const float* wcol = wsd + kthr * 8 + ((kthr >> 2) << 2);
        #pragma unroll 2
        for (int dc = 0; dc < 32; ++dc) {
            float4 xa  = *(float4*)(xs + dc * 128 + nthr * 8);
            float4 xb4 = *(float4*)(xs + dc * 128 + nthr * 8 + 4);
            float4 wlo = *(float4*)(wcol + dc * WROW);
            float4 whi = *(float4*)(wcol + dc * WROW + 4);
            float xr[8] = {xa.x, xa.y, xa.z, xa.w, xb4.x, xb4.y, xb4.z, xb4.w};
            float wr[8] = {wlo.x, wlo.y, wlo.z, wlo.w,
                           whi.x, whi.y, whi.z, whi.w};
            #pragma unroll
            for (int ni = 0; ni < 8; ++ni)
                #pragma unroll
                for (int ki = 0; ki < 8; ++ki)
                    acc[ni][ki] = fmaf(xr[ni], wr[ki], acc[ni][ki]);
        }
    }

    // ---- epilogue: distances, per-thread argmin over its 8 k's ------------
    float xsq_r[8], wsq_r[8];
    #pragma unroll
    for (int i = 0; i < 8; ++i) {
        xsq_r[i] = xsq_s[nthr * 8 + i];
        wsq_r[i] = wsq_s[kthr * 8 + i];
    }

    unsigned long long bp[8];
    #pragma unroll
    for (int ni = 0; ni < 8; ++ni) {
        float best = 3.4e38f;
        int bestk = 0;
        #pragma unroll
        for (int ki = 0; ki < 8; ++ki) {
            // mirror reference association: ((x_sq - 2xy) + w_sq) + 1e-8
            float t = xsq_r[ni] - 2.0f * acc[ni][ki];
            t += wsq_r[ki];
            t += 1e-8f;
            if (t < best) { best = t; bestk = k0 + kthr * 8 + ki; }
        }
        unsigned u = __float_as_uint(best);
        u = (u & 0x80000000u) ? ~u : (u | 0x80000000u);
        bp[ni] = ((unsigned long long)u << 32) | (unsigned)bestk;
    }

    // ---- block reduce over 16 kthr via LDS (reuse staging buffer) ---------
    __syncthreads();
    unsigned long long* ub = (unsigned long long*)sm;   // [16 kthr][128 n]
    #pragma unroll
    for (int ni = 0; ni < 8; ++ni)
        ub[kthr * 128 + nthr * 8 + ni] = bp[ni];
    __syncthreads();

    if (tid < 128) {
        unsigned long long m = ub[tid];
        #pragma unroll
        for (int j = 1; j < 16; ++j) {
            unsigned long long v = ub[j * 128 + tid];
            if (v < m) m = v;
        }
        atomicMin(&packed[n0 + tid], m);
    }
}

// ---------------- K3: combine -> indices, one-hot 1.0, counts ---------------
__global__ __launch_bounds__(256) void combine(
    const unsigned long long* __restrict__ packed,
    float* __restrict__ idxf, float* __restrict__ enc,
    float* __restrict__ counts)
{
    int n = blockIdx.x * 256 + threadIdx.x;
    unsigned k = (unsigned)(packed[n] & 0xFFFFFFFFu);
    idxf[n] = (float)k;
    enc[(size_t)n * K_CODES + k] = 1.0f;
    atomicAdd(&counts[k], 1.0f);
}

// ---------------- K4: gather -> quantized_st (NCHW) + per-block loss partial
__global__ __launch_bounds__(256) void quantize_loss(
    const float* __restrict__ x, const float* __restrict__ w,
    const float* __restrict__ idxf, float* __restrict__ outq,
    float* __restrict__ part)
{
    const int base4 = (blockIdx.x * 256 + threadIdx.x) * 4;
    float s = 0.f;
    #pragma unroll
    for (int i = 0; i < 4; ++i) {
        int e  = base4 + i * 1048576;      // NCHW element index (x4 aligned)
        int hw = e & 1023;
        int c  = (e >> 10) & 127;
        int b  = e >> 17;
        int n  = (b << 10) | hw;           // multiple of 4
        float4 xv = *(const float4*)(x + e);
        float4 kf = *(const float4*)(idxf + n);
        float q0 = w[(int)kf.x * DIM + c];
        float q1 = w[(int)kf.y * DIM + c];
        float q2 = w[(int)kf.z * DIM + c];
        float q3 = w[(int)kf.w * DIM + c];
        float4 df; df.x = q0 - xv.x; df.y = q1 - xv.y;
                   df.z = q2 - xv.z; df.w = q3 - xv.w;
        float4 o;  o.x = xv.x + df.x; o.y = xv.y + df.y;
                   o.z = xv.z + df.z; o.w = xv.w + df.w;
        *(float4*)(outq + e) = o;
        s = fmaf(df.x, df.x, s);
        s = fmaf(df.y, df.y, s);
        s = fmaf(df.z, df.z, s);
        s = fmaf(df.w, df.w, s);
    }
    #pragma unroll
    for (int o = 32; o > 0; o >>= 1) s += __shfl_down(s, o, 64);
    __shared__ float ls[4];
    if ((threadIdx.x & 63) == 0) ls[threadIdx.x >> 6] = s;
    __syncthreads();
    if (threadIdx.x == 0) part[blockIdx.x] = ls[0] + ls[1] + ls[2] + ls[3];
}

// ---------------- K5: loss (from partials) + perplexity ---------------------
__global__ __launch_bounds__(256) void finalize(
    const float* __restrict__ counts, const float* __restrict__ part,
    float* __restrict__ out)
{
    __shared__ float sh[512];
    float h = 0.f;
    for (int k = threadIdx.x; k < K_CODES; k += 256) {
        float p = counts[k] * (1.0f / N_FLAT);
        h += p * logf(p + 1e-10f);
    }
    float s = 0.f;
    for (int i = threadIdx.x; i < 1024; i += 256) s += part[i];
    sh[threadIdx.x] = h;
    sh[256 + threadIdx.x] = s;
    __syncthreads();
    #pragma unroll
    for (int st = 128; st > 0; st >>= 1) {
        if (threadIdx.x < st) {
            sh[threadIdx.x] += sh[threadIdx.x + st];
            sh[256 + threadIdx.x] += sh[256 + threadIdx.x + st];
        }
        __syncthreads();
    }
    if (threadIdx.x == 0) {
        float perp = expf(-sh[0]);
        float loss = 1.25f * (sh[256] / 4194304.0f);
        if (isnan(loss) || isinf(loss)) loss = 0.1f;
        out[OFF_LOSS] = loss;
        out[OFF_PERP] = perp;
    }
}

extern "C" void kernel_launch(void* const* d_in, const int* in_sizes, int n_in,
                              void* d_out, int out_size, void* d_ws, size_t ws_size,
                              hipStream_t stream) {
    const float* x = (const float*)d_in[0];   // [32,128,32,32] fp32 NCHW
    const float* w = (const float*)d_in[1];   // [4096,128] fp32
    float* out = (float*)d_out;
    char* ws = (char*)d_ws;

    unsigned long long* packed = (unsigned long long*)(ws + WS_PACKED);
    float* counts = (float*)(ws + WS_COUNTS);
    float* wsq    = (float*)(ws + WS_WSQ);
    float* xsq    = (float*)(ws + WS_XSQ);
    float* part   = (float*)(ws + WS_PART);

    // init workspace (poisoned 0xAA before every launch)
    hipMemsetAsync(packed, 0xFF, (size_t)N_FLAT * 8, stream);        // u64 max
    hipMemsetAsync(counts, 0, (size_t)K_CODES * 4, stream);

    wsq_kernel<<<K_CODES, 64, 0, stream>>>(w, wsq);
    xsq_kernel<<<N_FLAT / 256, 256, 0, stream>>>(x, xsq);

    dim3 g2(256, 32);
    dist_argmin<<<g2, 256, 0, stream>>>(x, w, wsq, xsq, packed, out + OFF_ENC);

    combine<<<N_FLAT / 256, 256, 0, stream>>>(packed, out + OFF_IDX,
                                              out + OFF_ENC, counts);

    quantize_loss<<<1024, 256, 0, stream>>>(x, w, out + OFF_IDX,
                                            out + OFF_Q, part);

    finalize<<<1, 256, 0, stream>>>(counts, part, out);
}

// Round 7
// 880.029 us; speedup vs baseline: 1.3444x; 1.3444x over previous
//
#include <hip/hip_runtime.h>
#include <stdint.h>
#include <math.h>

#define K_CODES 4096
#define DIM 128
#define N_FLAT 32768      // 32 * 32 * 32
#define HW 1024           // 32*32 spatial per batch

// output offsets (floats): quantized_st, loss, perplexity, encodings, indices
#define OFF_Q    0
#define OFF_LOSS 4194304
#define OFF_PERP 4194305
#define OFF_ENC  4194306
#define OFF_IDX  138412034

// workspace offsets (bytes)
#define WS_PACKED 0                        // 32768 * 8
#define WS_COUNTS 262144                   // 4096 * 4
#define WS_WSQ    278528                   // 4096 * 4
#define WS_XSQ    294912                   // 32768 * 4
#define WS_PART   425984                   // 1024 * 4
#define WS_XHL    430080                   // 32768 rows * 256 f16 = 16 MB (16B aligned)
#define WS_WHL    (WS_XHL + 16777216)      // 4096 rows * 256 f16 = 2 MB

typedef _Float16 f16x8 __attribute__((ext_vector_type(8)));
typedef float    f32x4 __attribute__((ext_vector_type(4)));

// f16 row layout in planes: [row][0:128]=h, [row][128:256]=l  (512 B/row)
// exact pow2 scales: x*32, w*1024 -> dot*2^15; keeps l-planes out of f16
// subnormal range (MFMA flush-safety) and unscaling is rounding-free.

// ---------------- K1: w_sq[k] = sum_d w[k][d]^2 (fp32, matches ref) --------
__global__ __launch_bounds__(64) void wsq_kernel(const float* __restrict__ w,
                                                 float* __restrict__ wsq) {
    int k = blockIdx.x;
    int lane = threadIdx.x;
    float a = w[k * DIM + lane];
    float b = w[k * DIM + lane + 64];
    float s = a * a + b * b;
    #pragma unroll
    for (int o = 32; o > 0; o >>= 1) s += __shfl_down(s, o, 64);
    if (lane == 0) wsq[k] = s;
}

// ---------------- K1b: x_sq[n] (fp32, strict c order) ----------------------
__global__ __launch_bounds__(256) void xsq_kernel(const float* __restrict__ x,
                                                  float* __restrict__ xsq) {
    int n = blockIdx.x * 256 + threadIdx.x;
    int b = n >> 10, hw = n & 1023;
    const float* xb = x + (size_t)b * (DIM * HW) + hw;
    float s = 0.f;
    #pragma unroll
    for (int c = 0; c < DIM; ++c) {
        float v = xb[c * HW];
        s = fmaf(v, v, s);
    }
    xsq[n] = s;
}

// ---------------- K1c: x -> f16 h/l planes, [n][d] rows (transpose) --------
__global__ __launch_bounds__(256) void xplanes_kernel(const float* __restrict__ x,
                                                      _Float16* __restrict__ xhl) {
    __shared__ float xt[128 * 65];            // [c][n], pad 65
    const int t = threadIdx.x;
    const int n0 = blockIdx.x * 64;
    const int b = n0 >> 10, hw0 = n0 & 1023;
    const float* xg = x + (size_t)b * (DIM * HW) + hw0;
    #pragma unroll
    for (int i = 0; i < 16; ++i) {
        int idx = i * 256 + t;                // 4096 float2
        int c = idx >> 5, n2 = (idx & 31) << 1;
        float2 v = *(const float2*)(xg + c * HW + n2);
        xt[c * 65 + n2] = v.x;
        xt[c * 65 + n2 + 1] = v.y;
    }
    __syncthreads();
    const int n = t >> 2, seg = t & 3;
    _Float16* row = xhl + (size_t)(n0 + n) * 256;
    #pragma unroll
    for (int q = 0; q < 4; ++q) {
        f16x8 hv, lv;
        #pragma unroll
        for (int j = 0; j < 8; ++j) {
            float v = 32.0f * xt[(seg * 32 + q * 8 + j) * 65 + n];
            _Float16 h = (_Float16)v;
            _Float16 l = (_Float16)(v - (float)h);
            hv[j] = h; lv[j] = l;
        }
        *(f16x8*)(row + seg * 32 + q * 8) = hv;
        *(f16x8*)(row + 128 + seg * 32 + q * 8) = lv;
    }
}

// ---------------- K1d: w -> f16 h/l planes, [k][d] rows --------------------
__global__ __launch_bounds__(256) void wplanes_kernel(const float* __restrict__ w,
                                                      _Float16* __restrict__ whl) {
    int T = blockIdx.x * 256 + threadIdx.x;
    int k = T >> 2, seg = T & 3;
    const float* wp = w + (size_t)k * DIM + seg * 32;
    _Float16* row = whl + (size_t)k * 256;
    #pragma unroll
    for (int q = 0; q < 4; ++q) {
        float4 a = *(const float4*)(wp + q * 8);
        float4 b = *(const float4*)(wp + q * 8 + 4);
        float vv[8] = {a.x, a.y, a.z, a.w, b.x, b.y, b.z, b.w};
        f16x8 hv, lv;
        #pragma unroll
        for (int j = 0; j < 8; ++j) {
            float v = 1024.0f * vv[j];
            _Float16 h = (_Float16)v;
            _Float16 l = (_Float16)(v - (float)h);
            hv[j] = h; lv[j] = l;
        }
        *(f16x8*)(row + seg * 32 + q * 8) = hv;
        *(f16x8*)(row + 128 + seg * 32 + q * 8) = lv;
    }
}

// ---------------- K2: MFMA distance GEMM + split-K argmin ------------------
// grid (256 n-tiles, 32 k-tiles), block 256 = 4 waves in 2x2.
// Wave tile 64n x 64k = 4x4 MFMA tiles of 16x16x32_f16. 3 MFMAs/tile/chunk
// (hH, hL, lH). d chunked by 32 through LDS. Layouts per m89/m120:
// A/B frag [m=lane&15][k=quad*8+j], C/D col=lane&15 row=quad*4+reg.
__global__ __launch_bounds__(256) void dist_argmin(
    const _Float16* __restrict__ xhl, const _Float16* __restrict__ whl,
    const float* __restrict__ wsq, const float* __restrict__ xsq,
    unsigned long long* __restrict__ packed, float* __restrict__ enc)
{
    // LDS rows: 72 f16 = 144 B stride (36 dw === 4 mod 32 -> balanced banks)
    __shared__ __align__(16) _Float16 xl[128 * 72];
    __shared__ __align__(16) _Float16 wl[128 * 72];
    __shared__ float xsq_s[128], wsq_s[128];
    __shared__ unsigned long long red[128][2];

    const int tid  = threadIdx.x;
    const int lane = tid & 63, wave = tid >> 6;
    const int lq   = lane & 15, quad = lane >> 4;
    const int wn0  = (wave >> 1) * 64, wk0 = (wave & 1) * 64;
    const int n0   = blockIdx.x * 128, k0 = blockIdx.y * 128;

    const int sr = tid >> 3, sh = (tid >> 2) & 1, sq = tid & 3;

    if (tid < 128) { xsq_s[tid] = xsq[n0 + tid]; wsq_s[tid] = wsq[k0 + tid]; }

    // zero-fill this block's 128x128 encodings rectangle (drains under MFMA)
    {
        float2 z2; z2.x = 0.f; z2.y = 0.f;
        float* ebase = enc + (size_t)n0 * K_CODES + k0;
        #pragma unroll 4
        for (int i = 0; i < 32; ++i) {
            int idx = i * 256 + tid;
            int r = idx >> 6, c2 = idx & 63;
            *(float2*)(ebase + (size_t)r * K_CODES + c2 * 2) = z2;
        }
    }

    f32x4 acc[4][4];
    #pragma unroll
    for (int i = 0; i < 4; ++i)
        #pragma unroll
        for (int j = 0; j < 4; ++j)
            acc[i][j] = (f32x4){0.f, 0.f, 0.f, 0.f};

    const _Float16* xbase = xhl + (size_t)n0 * 256;
    const _Float16* wbase = whl + (size_t)k0 * 256;

    #pragma unroll
    for (int c0 = 0; c0 < 4; ++c0) {
        if (c0 > 0) __syncthreads();
        // stage 32d chunk: per thread 4 X segs + 4 W segs (16 B each)
        #pragma unroll
        for (int i = 0; i < 4; ++i) {
            int r = sr + i * 32;
            int goff = r * 256 + sh * 128 + c0 * 32 + sq * 8;
            int loff = r * 72 + sh * 32 + sq * 8;
            *(f16x8*)(xl + loff) = *(const f16x8*)(xbase + goff);
            *(f16x8*)(wl + loff) = *(const f16x8*)(wbase + goff);
        }
        __syncthreads();

        f16x8 ah[4], al[4], bh[4], bl[4];
        #pragma unroll
        for (int i = 0; i < 4; ++i) {
            int xrow = (wn0 + i * 16 + lq) * 72 + quad * 8;
            ah[i] = *(const f16x8*)(xl + xrow);
            al[i] = *(const f16x8*)(xl + xrow + 32);
            int wrow = (wk0 + i * 16 + lq) * 72 + quad * 8;
            bh[i] = *(const f16x8*)(wl + wrow);
            bl[i] = *(const f16x8*)(wl + wrow + 32);
        }
        #pragma unroll
        for (int ki = 0; ki < 4; ++ki)
            #pragma unroll
            for (int ni = 0; ni < 4; ++ni) {
                acc[ni][ki] = __builtin_amdgcn_mfma_f32_16x16x32_f16(
                    ah[ni], bh[ki], acc[ni][ki], 0, 0, 0);
                acc[ni][ki] = __builtin_amdgcn_mfma_f32_16x16x32_f16(
                    ah[ni], bl[ki], acc[ni][ki], 0, 0, 0);
                acc[ni][ki] = __builtin_amdgcn_mfma_f32_16x16x32_f16(
                    al[ni], bh[ki], acc[ni][ki], 0, 0, 0);
            }
    }

    // ---- epilogue: distances + argmin. acc = 2^15 * dot; two_xy = acc*2^-14
    #pragma unroll
    for (int ni = 0; ni < 4; ++ni) {
        #pragma unroll
        for (int rg = 0; rg < 4; ++rg) {
            int rowl = wn0 + ni * 16 + quad * 4 + rg;   // block-local n
            float xr = xsq_s[rowl];
            float best = 3.4e38f; int bk = 0;
            #pragma unroll
            for (int ki = 0; ki < 4; ++ki) {
                int kl = wk0 + ki * 16 + lq;
                float t = xr - acc[ni][ki][rg] * 6.103515625e-05f;  // 2^-14
                t += wsq_s[kl];
                t += 1e-8f;
                if (t < best) { best = t; bk = k0 + kl; }
            }
            unsigned u = __float_as_uint(best);
            u = (u & 0x80000000u) ? ~u : (u | 0x80000000u);
            unsigned long long p = ((unsigned long long)u << 32) | (unsigned)bk;
            #pragma unroll
            for (int m = 1; m < 16; m <<= 1) {
                unsigned long long o = __shfl_xor(p, m, 64);
                if (o < p) p = o;
            }
            if (lq == 0) red[rowl][wave & 1] = p;
        }
    }
    __syncthreads();
    if (tid < 128) {
        unsigned long long a = red[tid][0], b = red[tid][1];
        atomicMin(&packed[n0 + tid], a < b ? a : b);
    }
}

// ---------------- K3: combine -> indices, one-hot 1.0, counts ---------------
__global__ __launch_bounds__(256) void combine(
    const unsigned long long* __restrict__ packed,
    float* __restrict__ idxf, float* __restrict__ enc,
    float* __restrict__ counts)
{
    int n = blockIdx.x * 256 + threadIdx.x;
    unsigned k = (unsigned)(packed[n] & 0xFFFFFFFFu);
    idxf[n] = (float)k;
    enc[(size_t)n * K_CODES + k] = 1.0f;
    atomicAdd(&counts[k], 1.0f);
}

// ---------------- K4: gather -> quantized_st (NCHW) + per-block loss partial
__global__ __launch_bounds__(256) void quantize_loss(
    const float* __restrict__ x, const float* __restrict__ w,
    const float* __restrict__ idxf, float* __restrict__ outq,
    float* __restrict__ part)
{
    const int base4 = (blockIdx.x * 256 + threadIdx.x) * 4;
    float s = 0.f;
    #pragma unroll
    for (int i = 0; i < 4; ++i) {
        int e  = base4 + i * 1048576;      // NCHW element index (x4 aligned)
        int hw = e & 1023;
        int c  = (e >> 10) & 127;
        int b  = e >> 17;
        int n  = (b << 10) | hw;           // multiple of 4
        float4 xv = *(const float4*)(x + e);
        float4 kf = *(const float4*)(idxf + n);
        float q0 = w[(int)kf.x * DIM + c];
        float q1 = w[(int)kf.y * DIM + c];
        float q2 = w[(int)kf.z * DIM + c];
        float q3 = w[(int)kf.w * DIM + c];
        float4 df; df.x = q0 - xv.x; df.y = q1 - xv.y;
                   df.z = q2 - xv.z; df.w = q3 - xv.w;
        float4 o;  o.x = xv.x + df.x; o.y = xv.y + df.y;
                   o.z = xv.z + df.z; o.w = xv.w + df.w;
        *(float4*)(outq + e) = o;
        s = fmaf(df.x, df.x, s);
        s = fmaf(df.y, df.y, s);
        s = fmaf(df.z, df.z, s);
        s = fmaf(df.w, df.w, s);
    }
    #pragma unroll
    for (int o = 32; o > 0; o >>= 1) s += __shfl_down(s, o, 64);
    __shared__ float ls[4];
    if ((threadIdx.x & 63) == 0) ls[threadIdx.x >> 6] = s;
    __syncthreads();
    if (threadIdx.x == 0) part[blockIdx.x] = ls[0] + ls[1] + ls[2] + ls[3];
}

// ---------------- K5: loss (from partials) + perplexity ---------------------
__global__ __launch_bounds__(256) void finalize(
    const float* __restrict__ counts, const float* __restrict__ part,
    float* __restrict__ out)
{
    __shared__ float sh[512];
    float h = 0.f;
    for (int k = threadIdx.x; k < K_CODES; k += 256) {
        float p = counts[k] * (1.0f / N_FLAT);
        h += p * logf(p + 1e-10f);
    }
    float s = 0.f;
    for (int i = threadIdx.x; i < 1024; i += 256) s += part[i];
    sh[threadIdx.x] = h;
    sh[256 + threadIdx.x] = s;
    __syncthreads();
    #pragma unroll
    for (int st = 128; st > 0; st >>= 1) {
        if (threadIdx.x < st) {
            sh[threadIdx.x] += sh[threadIdx.x + st];
            sh[256 + threadIdx.x] += sh[256 + threadIdx.x + st];
        }
        __syncthreads();
    }
    if (threadIdx.x == 0) {
        float perp = expf(-sh[0]);
        float loss = 1.25f * (sh[256] / 4194304.0f);
        if (isnan(loss) || isinf(loss)) loss = 0.1f;
        out[OFF_LOSS] = loss;
        out[OFF_PERP] = perp;
    }
}

extern "C" void kernel_launch(void* const* d_in, const int* in_sizes, int n_in,
                              void* d_out, int out_size, void* d_ws, size_t ws_size,
                              hipStream_t stream) {
    const float* x = (const float*)d_in[0];   // [32,128,32,32] fp32 NCHW
    const float* w = (const float*)d_in[1];   // [4096,128] fp32
    float* out = (float*)d_out;
    char* ws = (char*)d_ws;

    unsigned long long* packed = (unsigned long long*)(ws + WS_PACKED);
    float* counts = (float*)(ws + WS_COUNTS);
    float* wsq    = (float*)(ws + WS_WSQ);
    float* xsq    = (float*)(ws + WS_XSQ);
    float* part   = (float*)(ws + WS_PART);
    _Float16* xhl = (_Float16*)(ws + WS_XHL);
    _Float16* whl = (_Float16*)(ws + WS_WHL);

    hipMemsetAsync(packed, 0xFF, (size_t)N_FLAT * 8, stream);        // u64 max
    hipMemsetAsync(counts, 0, (size_t)K_CODES * 4, stream);

    wsq_kernel<<<K_CODES, 64, 0, stream>>>(w, wsq);
    xsq_kernel<<<N_FLAT / 256, 256, 0, stream>>>(x, xsq);
    xplanes_kernel<<<N_FLAT / 64, 256, 0, stream>>>(x, xhl);
    wplanes_kernel<<<K_CODES * 4 / 256, 256, 0, stream>>>(w, whl);

    dim3 g2(256, 32);
    dist_argmin<<<g2, 256, 0, stream>>>(xhl, whl, wsq, xsq, packed,
                                        out + OFF_ENC);

    combine<<<N_FLAT / 256, 256, 0, stream>>>(packed, out + OFF_IDX,
                                              out + OFF_ENC, counts);

    quantize_loss<<<1024, 256, 0, stream>>>(x, w, out + OFF_IDX,
                                            out + OFF_Q, part);

    finalize<<<1, 256, 0, stream>>>(counts, part, out);
}

// Round 8
// 845.404 us; speedup vs baseline: 1.3994x; 1.0410x over previous
//
#include <hip/hip_runtime.h>
#include <stdint.h>
#include <math.h>

#define K_CODES 4096
#define DIM 128
#define N_FLAT 32768      // 32 * 32 * 32
#define HW 1024           // 32*32 spatial per batch

// output offsets (floats): quantized_st, loss, perplexity, encodings, indices
#define OFF_Q    0
#define OFF_LOSS 4194304
#define OFF_PERP 4194305
#define OFF_ENC  4194306
#define OFF_IDX  138412034

// workspace offsets (bytes)
#define WS_PACKED 0                        // 32768 * 8
#define WS_COUNTS 262144                   // 4096 * 4
#define WS_WSQ    278528                   // 4096 * 4
#define WS_XSQ    294912                   // 32768 * 4
#define WS_PART   425984                   // 1024 * 4
#define WS_XHL    430080                   // 32768 rows * 256 f16 = 16 MB
#define WS_WHL    (WS_XHL + 16777216)      // 4096 rows * 256 f16 = 2 MB

typedef _Float16 f16x8 __attribute__((ext_vector_type(8)));
typedef float    f32x4 __attribute__((ext_vector_type(4)));

// f16 plane rows: [row][0:128]=h, [row][128:256]=l (512 B). Exact pow2
// scales x*32, w*1024 -> acc = 2^15*dot, unscale by 2^-14 is exact.

// ---------------- K1: w_sq + counts zero. grid 1024 x 256 (4 waves = 4 k) --
__global__ __launch_bounds__(256) void wsq_kernel(const float* __restrict__ w,
                                                  float* __restrict__ wsq,
                                                  float* __restrict__ counts) {
    int wave = threadIdx.x >> 6, lane = threadIdx.x & 63;
    int k = blockIdx.x * 4 + wave;
    float a = w[k * DIM + lane];
    float b = w[k * DIM + lane + 64];
    float s = a * a + b * b;
    #pragma unroll
    for (int o = 32; o > 0; o >>= 1) s += __shfl_down(s, o, 64);
    if (lane == 0) { wsq[k] = s; counts[k] = 0.f; }
}

// ---------------- K2: w -> f16 h/l planes ----------------------------------
__global__ __launch_bounds__(256) void wplanes_kernel(const float* __restrict__ w,
                                                      _Float16* __restrict__ whl) {
    int T = blockIdx.x * 256 + threadIdx.x;
    int k = T >> 2, seg = T & 3;
    const float* wp = w + (size_t)k * DIM + seg * 32;
    _Float16* row = whl + (size_t)k * 256;
    #pragma unroll
    for (int q = 0; q < 4; ++q) {
        float4 a = *(const float4*)(wp + q * 8);
        float4 b = *(const float4*)(wp + q * 8 + 4);
        float vv[8] = {a.x, a.y, a.z, a.w, b.x, b.y, b.z, b.w};
        f16x8 hv, lv;
        #pragma unroll
        for (int j = 0; j < 8; ++j) {
            float v = 1024.0f * vv[j];
            _Float16 h = (_Float16)v;
            _Float16 l = (_Float16)(v - (float)h);
            hv[j] = h; lv[j] = l;
        }
        *(f16x8*)(row + seg * 32 + q * 8) = hv;
        *(f16x8*)(row + 128 + seg * 32 + q * 8) = lv;
    }
}

// ---------------- K3: x -> planes + x_sq + packed init (fused) -------------
__global__ __launch_bounds__(256) void xprep_kernel(const float* __restrict__ x,
                                                    _Float16* __restrict__ xhl,
                                                    float* __restrict__ xsq,
                                                    unsigned long long* __restrict__ packed) {
    __shared__ float xt[128 * 65];            // [c][n], pad 65
    const int t = threadIdx.x;
    const int n0 = blockIdx.x * 64;
    const int b = n0 >> 10, hw0 = n0 & 1023;
    const float* xg = x + (size_t)b * (DIM * HW) + hw0;
    #pragma unroll
    for (int i = 0; i < 16; ++i) {
        int idx = i * 256 + t;                // 4096 float2
        int c = idx >> 5, n2 = (idx & 31) << 1;
        float2 v = *(const float2*)(xg + c * HW + n2);
        xt[c * 65 + n2] = v.x;
        xt[c * 65 + n2 + 1] = v.y;
    }
    __syncthreads();
    if (t < 64) {
        packed[n0 + t] = ~0ull;
        float s = 0.f;                        // strict c order, fp32 (== ref path)
        #pragma unroll
        for (int c = 0; c < DIM; ++c) {
            float v = xt[c * 65 + t];
            s = fmaf(v, v, s);
        }
        xsq[n0 + t] = s;
    }
    const int n = t >> 2, seg = t & 3;
    _Float16* row = xhl + (size_t)(n0 + n) * 256;
    #pragma unroll
    for (int q = 0; q < 4; ++q) {
        f16x8 hv, lv;
        #pragma unroll
        for (int j = 0; j < 8; ++j) {
            float v = 32.0f * xt[(seg * 32 + q * 8 + j) * 65 + n];
            _Float16 h = (_Float16)v;
            _Float16 l = (_Float16)(v - (float)h);
            hv[j] = h; lv[j] = l;
        }
        *(f16x8*)(row + seg * 32 + q * 8) = hv;
        *(f16x8*)(row + 128 + seg * 32 + q * 8) = lv;
    }
}

// ---------------- K4: MFMA distance GEMM + split-K argmin ------------------
// grid (256 n-tiles, 8 k-supertiles), block 256 = 4 waves 2x2. Each block:
// 128n x 512k via 4 sub-tiles of 128k (k-loop cuts xhl/whl L2-L3 re-reads
// 4x vs split-K 32). Wave tile 64x64 = 4x4 mfma_f32_16x16x32_f16, 3 MFMAs
// per tile (hH,hL,lH Dekker split). Layouts per m89/m120.
__global__ __launch_bounds__(256) void dist_argmin(
    const _Float16* __restrict__ xhl, const _Float16* __restrict__ whl,
    const float* __restrict__ wsq, const float* __restrict__ xsq,
    unsigned long long* __restrict__ packed, float* __restrict__ enc)
{
    __shared__ __align__(16) _Float16 xl[128 * 72];   // row stride 144 B
    __shared__ __align__(16) _Float16 wl[128 * 72];
    __shared__ float xsq_s[128], wsq_s[128];
    __shared__ unsigned long long red[128][2];

    const int tid  = threadIdx.x;
    const int lane = tid & 63, wave = tid >> 6;
    const int lq   = lane & 15, quad = lane >> 4;
    const int wn0  = (wave >> 1) * 64, wk0 = (wave & 1) * 64;
    const int n0   = blockIdx.x * 128;
    const int kbase = blockIdx.y * 512;

    const int sr = tid >> 3, sh = (tid >> 2) & 1, sq = tid & 3;

    // ---- zero-fill 128n x 512k encodings rect (float4, +2 shift for 16B
    // alignment; 2-float spill into next row is zero-over-zero benign; last
    // row's spill into idx region is overwritten later by combine) ----------
    {
        float* ebase = enc + (size_t)n0 * K_CODES + kbase;
        float4 z4; z4.x = z4.y = z4.z = z4.w = 0.f;
        #pragma unroll 8
        for (int i = 0; i < 64; ++i) {
            int idx = i * 256 + tid;
            int r = idx >> 7, c4 = idx & 127;
            *(float4*)(ebase + (size_t)r * K_CODES + 2 + c4 * 4) = z4;
        }
        if (tid < 128) {
            float2 z2; z2.x = 0.f; z2.y = 0.f;
            *(float2*)(ebase + (size_t)tid * K_CODES) = z2;
        }
    }

    if (tid < 128) xsq_s[tid] = xsq[n0 + tid];

    const _Float16* xbase = xhl + (size_t)n0 * 256;

    for (int ks = 0; ks < 4; ++ks) {
        const int k0 = kbase + ks * 128;
        if (tid < 128) wsq_s[tid] = wsq[k0 + tid];   // ordered by c0=0 barrier
        const _Float16* wbase = whl + (size_t)k0 * 256;

        f32x4 acc[4][4];
        #pragma unroll
        for (int i = 0; i < 4; ++i)
            #pragma unroll
            for (int j = 0; j < 4; ++j)
                acc[i][j] = (f32x4){0.f, 0.f, 0.f, 0.f};

        #pragma unroll
        for (int c0 = 0; c0 < 4; ++c0) {
            __syncthreads();
            #pragma unroll
            for (int i = 0; i < 4; ++i) {
                int r = sr + i * 32;
                int goff = r * 256 + sh * 128 + c0 * 32 + sq * 8;
                int loff = r * 72 + sh * 32 + sq * 8;
                *(f16x8*)(xl + loff) = *(const f16x8*)(xbase + goff);
                *(f16x8*)(wl + loff) = *(const f16x8*)(wbase + goff);
            }
            __syncthreads();

            f16x8 ah[4], al[4], bh[4], bl[4];
            #pragma unroll
            for (int i = 0; i < 4; ++i) {
                int xrow = (wn0 + i * 16 + lq) * 72 + quad * 8;
                ah[i] = *(const f16x8*)(xl + xrow);
                al[i] = *(const f16x8*)(xl + xrow + 32);
                int wrow = (wk0 + i * 16 + lq) * 72 + quad * 8;
                bh[i] = *(const f16x8*)(wl + wrow);
                bl[i] = *(const f16x8*)(wl + wrow + 32);
            }
            #pragma unroll
            for (int ki = 0; ki < 4; ++ki)
                #pragma unroll
                for (int ni = 0; ni < 4; ++ni) {
                    acc[ni][ki] = __builtin_amdgcn_mfma_f32_16x16x32_f16(
                        ah[ni], bh[ki], acc[ni][ki], 0, 0, 0);
                    acc[ni][ki] = __builtin_amdgcn_mfma_f32_16x16x32_f16(
                        ah[ni], bl[ki], acc[ni][ki], 0, 0, 0);
                    acc[ni][ki] = __builtin_amdgcn_mfma_f32_16x16x32_f16(
                        al[ni], bh[ki], acc[ni][ki], 0, 0, 0);
                }
        }

        // ---- epilogue: distances + argmin for this 128k sub-tile ----------
        #pragma unroll
        for (int ni = 0; ni < 4; ++ni) {
            #pragma unroll
            for (int rg = 0; rg < 4; ++rg) {
                int rowl = wn0 + ni * 16 + quad * 4 + rg;
                float xr = xsq_s[rowl];
                float best = 3.4e38f; int bk = 0;
                #pragma unroll
                for (int ki = 0; ki < 4; ++ki) {
                    int kl = wk0 + ki * 16 + lq;
                    float t = xr - acc[ni][ki][rg] * 6.103515625e-05f; // 2^-14
                    t += wsq_s[kl];
                    t += 1e-8f;
                    if (t < best) { best = t; bk = k0 + kl; }
                }
                unsigned u = __float_as_uint(best);
                u = (u & 0x80000000u) ? ~u : (u | 0x80000000u);
                unsigned long long p =
                    ((unsigned long long)u << 32) | (unsigned)bk;
                #pragma unroll
                for (int m = 1; m < 16; m <<= 1) {
                    unsigned long long o = __shfl_xor(p, m, 64);
                    if (o < p) p = o;
                }
                if (lq == 0) red[rowl][wave & 1] = p;
            }
        }
        __syncthreads();
        if (tid < 128) {
            unsigned long long a = red[tid][0], b = red[tid][1];
            atomicMin(&packed[n0 + tid], a < b ? a : b);
        }
    }
}

// ---------------- K5: combine -> indices, one-hot 1.0, counts ---------------
__global__ __launch_bounds__(256) void combine(
    const unsigned long long* __restrict__ packed,
    float* __restrict__ idxf, float* __restrict__ enc,
    float* __restrict__ counts)
{
    int n = blockIdx.x * 256 + threadIdx.x;
    unsigned k = (unsigned)(packed[n] & 0xFFFFFFFFu);
    idxf[n] = (float)k;
    enc[(size_t)n * K_CODES + k] = 1.0f;
    atomicAdd(&counts[k], 1.0f);
}

// ---------------- K6: gather -> quantized_st (NCHW) + per-block loss partial
__global__ __launch_bounds__(256) void quantize_loss(
    const float* __restrict__ x, const float* __restrict__ w,
    const float* __restrict__ idxf, float* __restrict__ outq,
    float* __restrict__ part)
{
    const int base4 = (blockIdx.x * 256 + threadIdx.x) * 4;
    float s = 0.f;
    #pragma unroll
    for (int i = 0; i < 4; ++i) {
        int e  = base4 + i * 1048576;      // NCHW element index (x4 aligned)
        int hw = e & 1023;
        int c  = (e >> 10) & 127;
        int b  = e >> 17;
        int n  = (b << 10) | hw;           // multiple of 4
        float4 xv = *(const float4*)(x + e);
        float4 kf = *(const float4*)(idxf + n);
        float q0 = w[(int)kf.x * DIM + c];
        float q1 = w[(int)kf.y * DIM + c];
        float q2 = w[(int)kf.z * DIM + c];
        float q3 = w[(int)kf.w * DIM + c];
        float4 df; df.x = q0 - xv.x; df.y = q1 - xv.y;
                   df.z = q2 - xv.z; df.w = q3 - xv.w;
        float4 o;  o.x = xv.x + df.x; o.y = xv.y + df.y;
                   o.z = xv.z + df.z; o.w = xv.w + df.w;
        *(float4*)(outq + e) = o;
        s = fmaf(df.x, df.x, s);
        s = fmaf(df.y, df.y, s);
        s = fmaf(df.z, df.z, s);
        s = fmaf(df.w, df.w, s);
    }
    #pragma unroll
    for (int o = 32; o > 0; o >>= 1) s += __shfl_down(s, o, 64);
    __shared__ float ls[4];
    if ((threadIdx.x & 63) == 0) ls[threadIdx.x >> 6] = s;
    __syncthreads();
    if (threadIdx.x == 0) part[blockIdx.x] = ls[0] + ls[1] + ls[2] + ls[3];
}

// ---------------- K7: loss (from partials) + perplexity ---------------------
__global__ __launch_bounds__(256) void finalize(
    const float* __restrict__ counts, const float* __restrict__ part,
    float* __restrict__ out)
{
    __shared__ float sh[512];
    float h = 0.f;
    for (int k = threadIdx.x; k < K_CODES; k += 256) {
        float p = counts[k] * (1.0f / N_FLAT);
        h += p * logf(p + 1e-10f);
    }
    float s = 0.f;
    for (int i = threadIdx.x; i < 1024; i += 256) s += part[i];
    sh[threadIdx.x] = h;
    sh[256 + threadIdx.x] = s;
    __syncthreads();
    #pragma unroll
    for (int st = 128; st > 0; st >>= 1) {
        if (threadIdx.x < st) {
            sh[threadIdx.x] += sh[threadIdx.x + st];
            sh[256 + threadIdx.x] += sh[256 + threadIdx.x + st];
        }
        __syncthreads();
    }
    if (threadIdx.x == 0) {
        float perp = expf(-sh[0]);
        float loss = 1.25f * (sh[256] / 4194304.0f);
        if (isnan(loss) || isinf(loss)) loss = 0.1f;
        out[OFF_LOSS] = loss;
        out[OFF_PERP] = perp;
    }
}

extern "C" void kernel_launch(void* const* d_in, const int* in_sizes, int n_in,
                              void* d_out, int out_size, void* d_ws, size_t ws_size,
                              hipStream_t stream) {
    const float* x = (const float*)d_in[0];   // [32,128,32,32] fp32 NCHW
    const float* w = (const float*)d_in[1];   // [4096,128] fp32
    float* out = (float*)d_out;
    char* ws = (char*)d_ws;

    unsigned long long* packed = (unsigned long long*)(ws + WS_PACKED);
    float* counts = (float*)(ws + WS_COUNTS);
    float* wsq    = (float*)(ws + WS_WSQ);
    float* xsq    = (float*)(ws + WS_XSQ);
    float* part   = (float*)(ws + WS_PART);
    _Float16* xhl = (_Float16*)(ws + WS_XHL);
    _Float16* whl = (_Float16*)(ws + WS_WHL);

    wsq_kernel<<<K_CODES / 4, 256, 0, stream>>>(w, wsq, counts);
    wplanes_kernel<<<K_CODES * 4 / 256, 256, 0, stream>>>(w, whl);
    xprep_kernel<<<N_FLAT / 64, 256, 0, stream>>>(x, xhl, xsq, packed);

    dim3 g2(256, 8);
    dist_argmin<<<g2, 256, 0, stream>>>(xhl, whl, wsq, xsq, packed,
                                        out + OFF_ENC);

    combine<<<N_FLAT / 256, 256, 0, stream>>>(packed, out + OFF_IDX,
                                              out + OFF_ENC, counts);

    quantize_loss<<<1024, 256, 0, stream>>>(x, w, out + OFF_IDX,
                                            out + OFF_Q, part);

    finalize<<<1, 256, 0, stream>>>(counts, part, out);
}